// Round 2
// baseline (7681.220 us; speedup 1.0000x reference)
//
#include <hip/hip_runtime.h>

// LSTM LM: S=512, B=32, H=D=1024, L=2, VOCAB=32000. ALL device tensors fp32
// (reference is jnp.float32); MFMA compute in bf16 with fp32 accumulation.
// Persistent producer-consumer kernel: 256 blocks (1/CU), teamA=layer0 (blocks
// 0-127), teamB=layer1 (blocks 128-255). Weights converted fp32->bf16 once into
// LDS in MFMA-fragment order. Hidden states published as bf16 into a ring of R
// slots in d_ws (R sized from ws_size, back-pressured), fp32 only to d_out.
// Sync: per-step counters; producer = agent-scope RELEASE add (L2 writeback),
// consumer = relaxed spin + one ACQUIRE load (L1/L2 invalidate) -> ring reuse safe.

typedef __bf16 bf16x8 __attribute__((ext_vector_type(8)));
typedef unsigned short u16x8 __attribute__((ext_vector_type(8)));
typedef float f32x4 __attribute__((ext_vector_type(4)));

#define NSTEPS 512
#define TEAM   128
#define OUT_ELEMS 16777216   // 512*32*1024 fp32 outputs
#define BH 32768             // 32*1024

// LDS: wfrag 131072 | sc 16896 | bias 128 | cst 1024 | toks 128
#define LDS_BYTES 149248
#define OFF_SC   131072
#define OFF_BIAS 147968
#define OFF_CST  148096
#define OFF_TOK  149120

__device__ __forceinline__ unsigned short f2b(float f) {
    unsigned int u = __float_as_uint(f);
    u += 0x7fffu + ((u >> 16) & 1u);   // RNE
    return (unsigned short)(u >> 16);
}
__device__ __forceinline__ float sigm(float x) { return 1.0f / (1.0f + __expf(-x)); }

__device__ __forceinline__ bf16x8 cvt8(const float* p) {
    float4 a = *(const float4*)p;
    float4 b = *(const float4*)(p + 4);
    u16x8 r;
    r[0] = f2b(a.x); r[1] = f2b(a.y); r[2] = f2b(a.z); r[3] = f2b(a.w);
    r[4] = f2b(b.x); r[5] = f2b(b.y); r[6] = f2b(b.z); r[7] = f2b(b.w);
    return __builtin_bit_cast(bf16x8, r);
}

__device__ __forceinline__ void wait_ge(unsigned int* p, unsigned int tgt) {
    while (__hip_atomic_load(p, __ATOMIC_RELAXED, __HIP_MEMORY_SCOPE_AGENT) < tgt)
        __builtin_amdgcn_s_sleep(2);
    (void)__hip_atomic_load(p, __ATOMIC_ACQUIRE, __HIP_MEMORY_SCOPE_AGENT); // inv caches
}

extern "C" __global__ __launch_bounds__(256, 1)
void lstm_persist(const int* __restrict__ tokens,
                  const float* __restrict__ h0in,
                  const float* __restrict__ c0in,
                  const float* __restrict__ emb,
                  const float* __restrict__ Wih0,
                  const float* __restrict__ Whh0,
                  const float* __restrict__ bih0,
                  const float* __restrict__ bhh0,
                  const float* __restrict__ Wih1,
                  const float* __restrict__ Whh1,
                  const float* __restrict__ bih1,
                  const float* __restrict__ bhh1,
                  float* __restrict__ dout,
                  unsigned short* __restrict__ h0b,   // ring: R slots x BH bf16
                  unsigned short* __restrict__ h1b,   // ring: R slots x BH bf16
                  unsigned int* __restrict__ cnt,     // cA[512], cB[512], cInit
                  int R)
{
    extern __shared__ char smem[];
    unsigned short* wfrag = (unsigned short*)smem;
    float* sc   = (float*)(smem + OFF_SC);
    float* bias = (float*)(smem + OFF_BIAS);
    float* cst  = (float*)(smem + OFF_CST);
    int*   toks = (int*)(smem + OFF_TOK);

    const int tid  = threadIdx.x;
    const int w    = tid >> 6;        // wave = K-quarter
    const int lane = tid & 63;
    const int lm   = lane & 15;
    const int lq   = lane >> 4;
    const int blk  = blockIdx.x;
    const bool tB  = (blk >= TEAM);   // teamB = layer 1
    const int bid  = tB ? blk - TEAM : blk;
    const int n0   = bid * 8;         // owned hidden units [n0, n0+8)

    const float* Wih = tB ? Wih1 : Wih0;
    const float* Whh = tB ? Whh1 : Whh0;
    const float* bi  = tB ? bih1 : bih0;
    const float* bh  = tB ? bhh1 : bhh0;
    unsigned int* cA = cnt;
    unsigned int* cB = cnt + 512;
    unsigned int* cInit = cnt + 1024;

    // ---- initial h (both layers) fp32 -> bf16 into ring slot R-1 ----
    {
        int idx = blk * 256 + tid;            // [0, 65536) covers [2,B,H]
        unsigned short v = f2b(h0in[idx]);
        int layer = idx >> 15, pos = idx & 32767;
        (layer ? h1b : h0b)[(size_t)(R - 1) * BH + pos] = v;
    }

    // ---- convert owned weight columns fp32->bf16 into frag-ordered LDS ----
    // chunk = (mat*2+nt)*32+ks ; lane holds W[col nt*16+n][ks*32 + q*8 .. +7]
    for (int t = tid; t < 8192; t += 256) {
        int chunk = t >> 6; int l = t & 63;
        int mat = chunk >> 6; int rem = chunk & 63;
        int nt = rem >> 5; int ks = rem & 31;
        int n = l & 15, q = l >> 4;
        int cl = nt * 16 + n;
        int grow = (cl >> 3) * 1024 + n0 + (cl & 7);
        const float* src = (mat ? Whh : Wih) + (size_t)grow * 1024 + ks * 32 + q * 8;
        *(bf16x8*)(wfrag + chunk * 512 + l * 8) = cvt8(src);
    }
    if (tid < 32) {
        int grow = (tid >> 3) * 1024 + n0 + (tid & 7);
        bias[tid] = bi[grow] + bh[grow];
    }
    {   // fp32 cell state, block-resident
        int u = tid & 7, b = tid >> 3;
        int loff = tB ? BH : 0;
        cst[b * 8 + u] = c0in[loff + b * 1024 + n0 + u];
    }
    __syncthreads();   // drains init-conv stores (vmcnt) + LDS
    if (tid == 0)
        __hip_atomic_fetch_add(cInit, 1u, __ATOMIC_RELEASE, __HIP_MEMORY_SCOPE_AGENT);

    f32x4 acc[2][2];
    bf16x8 pre[2][8];
    const f32x4 zero = {0.f, 0.f, 0.f, 0.f};

    for (int s = 0; s < NSTEPS; ++s) {
        const int slotPrev = (s + R - 1) % R;
        const int slotCur  = s % R;

        if (!tB) {
            if (tid < 32) toks[tid] = tokens[s * 32 + tid];
            __syncthreads();
            #pragma unroll
            for (int mt = 0; mt < 2; ++mt) {
                const float* rowp = emb + (size_t)toks[mt * 16 + lm] * 1024 + lq * 8;
                #pragma unroll
                for (int i = 0; i < 8; ++i)
                    pre[mt][i] = cvt8(rowp + (w * 8 + i) * 32);
            }
            if (tid == 0) {
                if (s > 0) wait_ge(&cA[s - 1], TEAM);
                else       wait_ge(cInit, 256);
                if (s >= R) wait_ge(&cB[s - R], TEAM);  // ring back-pressure
            }
            __syncthreads();
        } else {
            if (tid == 0) {
                if (s > 0) wait_ge(&cB[s - 1], TEAM);
                else       wait_ge(cInit, 256);
            }
            __syncthreads();
            const unsigned short* h1src = h1b + (size_t)slotPrev * BH;
            #pragma unroll
            for (int mt = 0; mt < 2; ++mt) {
                #pragma unroll
                for (int i = 0; i < 8; ++i)
                    pre[mt][i] = *(const bf16x8*)(h1src + (mt * 16 + lm) * 1024 + (w * 8 + i) * 32 + lq * 8);
            }
            if (tid == 0) wait_ge(&cA[s], TEAM);
            __syncthreads();
        }

        // stream source (bf16 ring) + LDS matrix pairing
        const unsigned short* hs;
        int preMat, strMat;
        if (!tB) { hs = h0b + (size_t)slotPrev * BH; preMat = 0; strMat = 1; }
        else     { hs = h0b + (size_t)slotCur  * BH; preMat = 1; strMat = 0; }

        acc[0][0] = zero; acc[0][1] = zero; acc[1][0] = zero; acc[1][1] = zero;

        #pragma unroll
        for (int i = 0; i < 8; ++i) {
            int ks = w * 8 + i;
            bf16x8 a0 = *(const bf16x8*)(hs + (0 * 16 + lm) * 1024 + ks * 32 + lq * 8);
            bf16x8 a1 = *(const bf16x8*)(hs + (1 * 16 + lm) * 1024 + ks * 32 + lq * 8);
            bf16x8 bp0 = *(const bf16x8*)(wfrag + ((preMat * 2 + 0) * 32 + ks) * 512 + lane * 8);
            bf16x8 bp1 = *(const bf16x8*)(wfrag + ((preMat * 2 + 1) * 32 + ks) * 512 + lane * 8);
            bf16x8 bs0 = *(const bf16x8*)(wfrag + ((strMat * 2 + 0) * 32 + ks) * 512 + lane * 8);
            bf16x8 bs1 = *(const bf16x8*)(wfrag + ((strMat * 2 + 1) * 32 + ks) * 512 + lane * 8);
            acc[0][0] = __builtin_amdgcn_mfma_f32_16x16x32_bf16(pre[0][i], bp0, acc[0][0], 0, 0, 0);
            acc[0][1] = __builtin_amdgcn_mfma_f32_16x16x32_bf16(pre[0][i], bp1, acc[0][1], 0, 0, 0);
            acc[1][0] = __builtin_amdgcn_mfma_f32_16x16x32_bf16(pre[1][i], bp0, acc[1][0], 0, 0, 0);
            acc[1][1] = __builtin_amdgcn_mfma_f32_16x16x32_bf16(pre[1][i], bp1, acc[1][1], 0, 0, 0);
            acc[0][0] = __builtin_amdgcn_mfma_f32_16x16x32_bf16(a0, bs0, acc[0][0], 0, 0, 0);
            acc[0][1] = __builtin_amdgcn_mfma_f32_16x16x32_bf16(a0, bs1, acc[0][1], 0, 0, 0);
            acc[1][0] = __builtin_amdgcn_mfma_f32_16x16x32_bf16(a1, bs0, acc[1][0], 0, 0, 0);
            acc[1][1] = __builtin_amdgcn_mfma_f32_16x16x32_bf16(a1, bs1, acc[1][1], 0, 0, 0);
        }

        // cross-wave K reduction via padded LDS (C layout: col=lane&15, row=quad*4+reg)
        #pragma unroll
        for (int mt = 0; mt < 2; ++mt) {
            #pragma unroll
            for (int nt = 0; nt < 2; ++nt) {
                f32x4 a = acc[mt][nt];
                int col = nt * 16 + lm;
                int rb = w * 32 + mt * 16 + lq * 4;
                sc[(rb + 0) * 33 + col] = a[0];
                sc[(rb + 1) * 33 + col] = a[1];
                sc[(rb + 2) * 33 + col] = a[2];
                sc[(rb + 3) * 33 + col] = a[3];
            }
        }
        __syncthreads();

        // epilogue: gates -> (h,c) for owned 8 units x 32 batch
        {
            int u = tid & 7, b = tid >> 3;
            float G[4];
            #pragma unroll
            for (int g = 0; g < 4; ++g) {
                int col = g * 8 + u;
                float v = bias[col];
                #pragma unroll
                for (int w2 = 0; w2 < 4; ++w2) v += sc[(w2 * 32 + b) * 33 + col];
                G[g] = v;
            }
            float ig = sigm(G[0]);
            float fg = sigm(G[1]);
            float gg = tanhf(G[2]);
            float og = sigm(G[3]);
            float cOld = cst[b * 8 + u];
            float cNew = fg * cOld + ig * gg;
            float hNew = og * tanhf(cNew);
            cst[b * 8 + u] = cNew;
            unsigned short hb = f2b(hNew);
            int off = b * 1024 + n0 + u;
            if (!tB) {
                h0b[(size_t)slotCur * BH + off] = hb;
                if (s == NSTEPS - 1) {
                    dout[OUT_ELEMS + off] = hNew;              // hF layer0
                    dout[OUT_ELEMS + 2 * BH + off] = cNew;     // cF layer0
                }
            } else {
                dout[(size_t)s * BH + off] = hNew;             // outputs [S,B,H]
                h1b[(size_t)slotCur * BH + off] = hb;
                if (s == NSTEPS - 1) {
                    dout[OUT_ELEMS + BH + off] = hNew;         // hF layer1
                    dout[OUT_ELEMS + 3 * BH + off] = cNew;     // cF layer1
                }
            }
        }
        __syncthreads();   // drains stores (compiler emits vmcnt(0) before s_barrier)
        if (tid == 0)
            __hip_atomic_fetch_add(tB ? &cB[s] : &cA[s], 1u, __ATOMIC_RELEASE, __HIP_MEMORY_SCOPE_AGENT);
    }
}

extern "C" void kernel_launch(void* const* d_in, const int* in_sizes, int n_in,
                              void* d_out, int out_size, void* d_ws, size_t ws_size,
                              hipStream_t stream) {
    hipFuncSetAttribute((const void*)lstm_persist,
                        hipFuncAttributeMaxDynamicSharedMemorySize, LDS_BYTES);
    hipMemsetAsync(d_ws, 0, 4096, stream);   // cA[512] + cB[512] + cInit

    const int* tokens = (const int*)d_in[0];
    const float* h0   = (const float*)d_in[1];
    const float* c0   = (const float*)d_in[2];
    const float* emb  = (const float*)d_in[3];
    const float* Wih0 = (const float*)d_in[4];
    const float* Whh0 = (const float*)d_in[5];
    const float* bih0 = (const float*)d_in[6];
    const float* bhh0 = (const float*)d_in[7];
    const float* Wih1 = (const float*)d_in[8];
    const float* Whh1 = (const float*)d_in[9];
    const float* bih1 = (const float*)d_in[10];
    const float* bhh1 = (const float*)d_in[11];

    // ring size from ws_size (constant across calls -> same work every call)
    long long avail = (long long)ws_size - 4096;
    int R = (int)(avail / (2LL * BH * 2));   // two rings, 64KB/slot each
    if (R > NSTEPS) R = NSTEPS;
    if (R < 2) R = 2;

    unsigned int* cnt = (unsigned int*)d_ws;
    unsigned short* h0b = (unsigned short*)((char*)d_ws + 4096);
    unsigned short* h1b = h0b + (size_t)R * BH;

    lstm_persist<<<dim3(256), dim3(256), LDS_BYTES, stream>>>(
        tokens, h0, c0, emb, Wih0, Whh0, bih0, bhh0, Wih1, Whh1, bih1, bhh1,
        (float*)d_out, h0b, h1b, cnt, R);
}

// Round 3
// 5157.204 us; speedup vs baseline: 1.4894x; 1.4894x over previous
//
#include <hip/hip_runtime.h>

// LSTM LM: S=512, B=32, H=D=1024, L=2 (fp32 tensors; bf16 MFMA compute).
// Persistent 2-team pipeline (A=layer0 blocks 0-127, B=layer1 blocks 128-255),
// weights LDS-resident. Round-3 sync design: ZERO cache-maintenance ops.
//  - h ring slots written with write-through stores (sc0 sc1 -> MALL) and read
//    with L1/L2-bypassing loads (sc0 sc1) => ring reuse safe at any R.
//  - per-block flag dwords (no RMW contention): producer stores s+2 relaxed
//    agent (write-through); consumers spin per-producer with relaxed agent loads.
//  - explicit s_waitcnt vmcnt(0) before the barrier preceding each flag store
//    (asm stores are outside compiler vmcnt bookkeeping).

typedef __bf16 bf16x8 __attribute__((ext_vector_type(8)));
typedef unsigned short u16x8 __attribute__((ext_vector_type(8)));
typedef float f32x4 __attribute__((ext_vector_type(4)));

#define NSTEPS 512
#define TEAM   128
#define OUT_ELEMS 16777216   // 512*32*1024 fp32 outputs
#define BH 32768             // 32*1024

// LDS: wfrag 131072 | sc 16896 | bias 128 | cst 1024 | toks 128
#define LDS_BYTES 149248
#define OFF_SC   131072
#define OFF_BIAS 147968
#define OFF_CST  148096
#define OFF_TOK  149120

__device__ __forceinline__ unsigned short f2b(float f) {
    unsigned int u = __float_as_uint(f);
    u += 0x7fffu + ((u >> 16) & 1u);   // RNE
    return (unsigned short)(u >> 16);
}
__device__ __forceinline__ float sigm(float x) { return 1.0f / (1.0f + __expf(-x)); }

__device__ __forceinline__ bf16x8 cvt8(const float* p) {
    float4 a = *(const float4*)p;
    float4 b = *(const float4*)(p + 4);
    u16x8 r;
    r[0] = f2b(a.x); r[1] = f2b(a.y); r[2] = f2b(a.z); r[3] = f2b(a.w);
    r[4] = f2b(b.x); r[5] = f2b(b.y); r[6] = f2b(b.z); r[7] = f2b(b.w);
    return __builtin_bit_cast(bf16x8, r);
}

// ---- coherence-point (MALL) access primitives: no cache maintenance needed ----
__device__ __forceinline__ bf16x8 ld_mall16(const unsigned short* p) {
    uint4 r;
    asm volatile("global_load_dwordx4 %0, %1, off sc0 sc1" : "=v"(r) : "v"(p));
    return __builtin_bit_cast(bf16x8, r);
}
__device__ __forceinline__ void st_mall2(unsigned short* p, unsigned int v) {
    asm volatile("global_store_short %0, %1, off sc0 sc1" :: "v"(p), "v"(v) : "memory");
}
__device__ __forceinline__ void wait_vm0() {
    asm volatile("s_waitcnt vmcnt(0)" ::: "memory");
}
__device__ __forceinline__ unsigned int flag_ld(const unsigned int* p) {
    return __hip_atomic_load(p, __ATOMIC_RELAXED, __HIP_MEMORY_SCOPE_AGENT);
}
__device__ __forceinline__ void flag_st(unsigned int* p, unsigned int v) {
    __hip_atomic_store(p, v, __ATOMIC_RELAXED, __HIP_MEMORY_SCOPE_AGENT);
}

extern "C" __global__ __launch_bounds__(256, 1)
void lstm_persist(const int* __restrict__ tokens,
                  const float* __restrict__ h0in,
                  const float* __restrict__ c0in,
                  const float* __restrict__ emb,
                  const float* __restrict__ Wih0,
                  const float* __restrict__ Whh0,
                  const float* __restrict__ bih0,
                  const float* __restrict__ bhh0,
                  const float* __restrict__ Wih1,
                  const float* __restrict__ Whh1,
                  const float* __restrict__ bih1,
                  const float* __restrict__ bhh1,
                  float* __restrict__ dout,
                  unsigned short* __restrict__ h0b,   // ring: R x BH bf16
                  unsigned short* __restrict__ h1b,   // ring: R x BH bf16
                  unsigned int* __restrict__ cnt,     // flagA[128], flagB[128]
                  int R)
{
    extern __shared__ char smem[];
    unsigned short* wfrag = (unsigned short*)smem;
    float* sc   = (float*)(smem + OFF_SC);
    float* bias = (float*)(smem + OFF_BIAS);
    float* cst  = (float*)(smem + OFF_CST);
    int*   toks = (int*)(smem + OFF_TOK);

    const int tid  = threadIdx.x;
    const int w    = tid >> 6;        // wave = K-quarter
    const int lane = tid & 63;
    const int lm   = lane & 15;
    const int lq   = lane >> 4;
    const int blk  = blockIdx.x;
    const bool tB  = (blk >= TEAM);   // teamB = layer 1
    const int bid  = tB ? blk - TEAM : blk;
    const int n0   = bid * 8;         // owned hidden units [n0, n0+8)

    const float* Wih = tB ? Wih1 : Wih0;
    const float* Whh = tB ? Whh1 : Whh0;
    const float* bi  = tB ? bih1 : bih0;
    const float* bh  = tB ? bhh1 : bhh0;
    unsigned int* flagA = cnt;
    unsigned int* flagB = cnt + TEAM;
    unsigned int* myflag = (tB ? flagB : flagA) + bid;

    // ---- initial h for OWN production region -> ring slot R-1 (write-through) ----
    {
        int u = tid & 7, b = tid >> 3;
        int loff = tB ? BH : 0;
        unsigned short v = f2b(h0in[loff + b * 1024 + n0 + u]);
        st_mall2((tB ? h1b : h0b) + (size_t)(R - 1) * BH + b * 1024 + n0 + u, (unsigned int)v);
    }

    // ---- convert owned weight columns fp32->bf16 into frag-ordered LDS ----
    // chunk = (mat*2+nt)*32+ks ; lane holds W[col nt*16+n][ks*32 + q*8 .. +7]
    for (int t = tid; t < 8192; t += 256) {
        int chunk = t >> 6; int l = t & 63;
        int mat = chunk >> 6; int rem = chunk & 63;
        int nt = rem >> 5; int ks = rem & 31;
        int n = l & 15, q = l >> 4;
        int cl = nt * 16 + n;
        int grow = (cl >> 3) * 1024 + n0 + (cl & 7);
        const float* src = (mat ? Whh : Wih) + (size_t)grow * 1024 + ks * 32 + q * 8;
        *(bf16x8*)(wfrag + chunk * 512 + l * 8) = cvt8(src);
    }
    if (tid < 32) {
        int grow = (tid >> 3) * 1024 + n0 + (tid & 7);
        bias[tid] = bi[grow] + bh[grow];
    }
    {   // fp32 cell state, block-resident
        int u = tid & 7, b = tid >> 3;
        int loff = tB ? BH : 0;
        cst[b * 8 + u] = c0in[loff + b * 1024 + n0 + u];
    }
    wait_vm0();          // drain asm init stores (outside compiler bookkeeping)
    __syncthreads();
    if (tid == 0) flag_st(myflag, 1u);   // flag==k  =>  h[k-2] published

    f32x4 acc[2][2];
    bf16x8 pre[2][8];
    bf16x8 sa[2][8];
    const f32x4 zero = {0.f, 0.f, 0.f, 0.f};

    for (int s = 0; s < NSTEPS; ++s) {
        const int slotPrev = (s + R - 1) % R;
        const int slotCur  = s % R;
        const unsigned short* hs;   // stream source (read at MALL)
        int preMat, strMat;

        if (!tB) {
            // ---- team A: emb gather (cached) while peers finish step s-1 ----
            if (tid < 32) toks[tid] = tokens[s * 32 + tid];
            __syncthreads();
            #pragma unroll
            for (int mt = 0; mt < 2; ++mt) {
                const float* rowp = emb + (size_t)toks[mt * 16 + lm] * 1024 + lq * 8;
                #pragma unroll
                for (int i = 0; i < 8; ++i)
                    pre[mt][i] = cvt8(rowp + (w * 8 + i) * 32);
            }
            // poll: all A peers done step s-1; back-pressure vs team B at distance R
            if (tid < TEAM) {
                unsigned int tgt = (unsigned int)(s + 1);
                while (flag_ld(&flagA[tid]) < tgt) __builtin_amdgcn_s_sleep(1);
            } else if (s >= R) {
                unsigned int tgt = (unsigned int)(s - R + 2);
                while (flag_ld(&flagB[tid - TEAM]) < tgt) __builtin_amdgcn_s_sleep(1);
            }
            __syncthreads();
            hs = h0b + (size_t)slotPrev * BH;  preMat = 0; strMat = 1;
        } else {
            // ---- team B: h1[s-1] then h0[s] ----
            if (tid < TEAM) {
                unsigned int tgt = (unsigned int)(s + 1);
                while (flag_ld(&flagB[tid]) < tgt) __builtin_amdgcn_s_sleep(1);
            }
            __syncthreads();
            const unsigned short* h1src = h1b + (size_t)slotPrev * BH;
            #pragma unroll
            for (int mt = 0; mt < 2; ++mt)
                #pragma unroll
                for (int i = 0; i < 8; ++i)
                    pre[mt][i] = ld_mall16(h1src + (mt * 16 + lm) * 1024 + (w * 8 + i) * 32 + lq * 8);
            if (tid < TEAM) {
                unsigned int tgt = (unsigned int)(s + 2);
                while (flag_ld(&flagA[tid]) < tgt) __builtin_amdgcn_s_sleep(1);
            }
            __syncthreads();
            hs = h0b + (size_t)slotCur * BH;  preMat = 1; strMat = 0;
        }

        // ---- issue all stream fragments (MALL reads), single drain ----
        #pragma unroll
        for (int mt = 0; mt < 2; ++mt)
            #pragma unroll
            for (int i = 0; i < 8; ++i)
                sa[mt][i] = ld_mall16(hs + (mt * 16 + lm) * 1024 + (w * 8 + i) * 32 + lq * 8);
        wait_vm0();

        acc[0][0] = zero; acc[0][1] = zero; acc[1][0] = zero; acc[1][1] = zero;

        #pragma unroll
        for (int i = 0; i < 8; ++i) {
            int ks = w * 8 + i;
            bf16x8 bp0 = *(const bf16x8*)(wfrag + ((preMat * 2 + 0) * 32 + ks) * 512 + lane * 8);
            bf16x8 bp1 = *(const bf16x8*)(wfrag + ((preMat * 2 + 1) * 32 + ks) * 512 + lane * 8);
            bf16x8 bs0 = *(const bf16x8*)(wfrag + ((strMat * 2 + 0) * 32 + ks) * 512 + lane * 8);
            bf16x8 bs1 = *(const bf16x8*)(wfrag + ((strMat * 2 + 1) * 32 + ks) * 512 + lane * 8);
            acc[0][0] = __builtin_amdgcn_mfma_f32_16x16x32_bf16(pre[0][i], bp0, acc[0][0], 0, 0, 0);
            acc[0][1] = __builtin_amdgcn_mfma_f32_16x16x32_bf16(pre[0][i], bp1, acc[0][1], 0, 0, 0);
            acc[1][0] = __builtin_amdgcn_mfma_f32_16x16x32_bf16(pre[1][i], bp0, acc[1][0], 0, 0, 0);
            acc[1][1] = __builtin_amdgcn_mfma_f32_16x16x32_bf16(pre[1][i], bp1, acc[1][1], 0, 0, 0);
            acc[0][0] = __builtin_amdgcn_mfma_f32_16x16x32_bf16(sa[0][i], bs0, acc[0][0], 0, 0, 0);
            acc[0][1] = __builtin_amdgcn_mfma_f32_16x16x32_bf16(sa[0][i], bs1, acc[0][1], 0, 0, 0);
            acc[1][0] = __builtin_amdgcn_mfma_f32_16x16x32_bf16(sa[1][i], bs0, acc[1][0], 0, 0, 0);
            acc[1][1] = __builtin_amdgcn_mfma_f32_16x16x32_bf16(sa[1][i], bs1, acc[1][1], 0, 0, 0);
        }

        // cross-wave K reduction via padded LDS (C layout: col=lane&15, row=quad*4+reg)
        #pragma unroll
        for (int mt = 0; mt < 2; ++mt) {
            #pragma unroll
            for (int nt = 0; nt < 2; ++nt) {
                f32x4 a = acc[mt][nt];
                int col = nt * 16 + lm;
                int rb = w * 32 + mt * 16 + lq * 4;
                sc[(rb + 0) * 33 + col] = a[0];
                sc[(rb + 1) * 33 + col] = a[1];
                sc[(rb + 2) * 33 + col] = a[2];
                sc[(rb + 3) * 33 + col] = a[3];
            }
        }
        __syncthreads();

        // epilogue: gates -> (h,c) for owned 8 units x 32 batch
        {
            int u = tid & 7, b = tid >> 3;
            float G[4];
            #pragma unroll
            for (int g = 0; g < 4; ++g) {
                int col = g * 8 + u;
                float v = bias[col];
                #pragma unroll
                for (int w2 = 0; w2 < 4; ++w2) v += sc[(w2 * 32 + b) * 33 + col];
                G[g] = v;
            }
            float ig = sigm(G[0]);
            float fg = sigm(G[1]);
            float gg = tanhf(G[2]);
            float og = sigm(G[3]);
            float cOld = cst[b * 8 + u];
            float cNew = fg * cOld + ig * gg;
            float hNew = og * tanhf(cNew);
            cst[b * 8 + u] = cNew;
            unsigned short hb = f2b(hNew);
            int off = b * 1024 + n0 + u;
            if (!tB) {
                st_mall2(h0b + (size_t)slotCur * BH + off, (unsigned int)hb);
                if (s == NSTEPS - 1) {
                    dout[OUT_ELEMS + off] = hNew;              // hF layer0
                    dout[OUT_ELEMS + 2 * BH + off] = cNew;     // cF layer0
                }
            } else {
                dout[(size_t)s * BH + off] = hNew;             // outputs [S,B,H]
                st_mall2(h1b + (size_t)slotCur * BH + off, (unsigned int)hb);
                if (s == NSTEPS - 1) {
                    dout[OUT_ELEMS + BH + off] = hNew;         // hF layer1
                    dout[OUT_ELEMS + 3 * BH + off] = cNew;     // cF layer1
                }
            }
        }
        wait_vm0();        // asm h stores drained to MALL before signalling
        __syncthreads();
        if (tid == 0) flag_st(myflag, (unsigned int)(s + 2));
    }
}

extern "C" void kernel_launch(void* const* d_in, const int* in_sizes, int n_in,
                              void* d_out, int out_size, void* d_ws, size_t ws_size,
                              hipStream_t stream) {
    hipFuncSetAttribute((const void*)lstm_persist,
                        hipFuncAttributeMaxDynamicSharedMemorySize, LDS_BYTES);
    hipMemsetAsync(d_ws, 0, 4096, stream);   // flagA[128] + flagB[128] (+pad)

    const int* tokens = (const int*)d_in[0];
    const float* h0   = (const float*)d_in[1];
    const float* c0   = (const float*)d_in[2];
    const float* emb  = (const float*)d_in[3];
    const float* Wih0 = (const float*)d_in[4];
    const float* Whh0 = (const float*)d_in[5];
    const float* bih0 = (const float*)d_in[6];
    const float* bhh0 = (const float*)d_in[7];
    const float* Wih1 = (const float*)d_in[8];
    const float* Whh1 = (const float*)d_in[9];
    const float* bih1 = (const float*)d_in[10];
    const float* bhh1 = (const float*)d_in[11];

    // ring size from ws_size (constant across calls). Reuse is coherence-safe
    // at any R (MALL-through access); R only sets pipeline slack.
    long long avail = (long long)ws_size - 4096;
    long long r = avail / (2LL * BH * 2);
    int R = (int)(r > NSTEPS ? NSTEPS : r);
    if (R < 2) R = 2;

    unsigned int* cnt = (unsigned int*)d_ws;
    unsigned short* h0b = (unsigned short*)((char*)d_ws + 4096);
    unsigned short* h1b = h0b + (size_t)R * BH;

    lstm_persist<<<dim3(256), dim3(256), LDS_BYTES, stream>>>(
        tokens, h0, c0, emb, Wih0, Whh0, bih0, bhh0, Wih1, Whh1, bih1, bhh1,
        (float*)d_out, h0b, h1b, cnt, R);
}